// Round 16
// baseline (53.643 us; speedup 1.0000x reference)
//
#include <hip/hip_runtime.h>
#include <hip/hip_bf16.h>

// Problem constants (N, M, D, A) = (10000, 32, 256, 128)
#define NROW 10000
#define MANC 32
#define DIM  256
#define ADIM 128

typedef __attribute__((ext_vector_type(8))) short short8;
typedef __attribute__((ext_vector_type(4))) float floatx4;
typedef __attribute__((ext_vector_type(2))) unsigned int uint2v;

#if __has_builtin(__builtin_amdgcn_exp2f)
#define EXP2F(x) __builtin_amdgcn_exp2f(x)
#else
#define EXP2F(x) __expf((x) * 0.69314718055994531f)
#endif

#define C2L2E 2.8853900817779268f   // 2*log2(e)
#define L2E   1.4426950408889634f   // log2(e)

static __device__ __forceinline__ short f2bf(float x) {
    union { __hip_bfloat16 h; short s; } u;
    u.h = __float2bfloat16(x);
    return u.s;
}
static __device__ __forceinline__ float bf2f(unsigned short u) {
    return __uint_as_float(((unsigned int)u) << 16);
}

// ---------------------------------------------------------------------------
// proj: SP[n][j] = be[n] . W2[j], PRE-BAKED: self cols get (acc+bias)*2log2e,
// anc cols get acc*2log2e (bias folded in f32 before the single bf16 round).
// Block = 4 waves = 64 rows x 64-col quarter; W staged via XOR-swizzled LDS;
// q==0 blocks emit beb as a side product. Unchanged from R13-R15.
// ---------------------------------------------------------------------------
__global__ __launch_bounds__(256) void proj_kernel(
    const float* __restrict__ be, const float* __restrict__ Wp,
    const float* __restrict__ bias,
    __hip_bfloat16* __restrict__ SP, __hip_bfloat16* __restrict__ beb) {
    __shared__ short lds[64 * 256];          // 32 KB: 64 W2-rows x 256 k (bf16)
    int q  = blockIdx.x & 3;                 // col quarter
    int rb = blockIdx.x >> 2;                // row block 0..156
    int t  = threadIdx.x;

    // ---- stage W quarter: rows j = q*64 .. q*64+63 ----
#pragma unroll
    for (int i = 0; i < 8; ++i) {
        int c  = i * 256 + t;                // 16B chunk id 0..2047
        int jl = c >> 5;                     // local row 0..63
        int e0 = (c & 31) * 8;               // elem offset 0..248
        int j  = q * 64 + jl;
        const float* src = (j < ADIM) ? (Wp + (size_t)j * (2 * DIM) + e0)
                                      : (Wp + (size_t)(j - ADIM) * (2 * DIM) + DIM + e0);
        floatx4 v0 = *(const floatx4*)src;
        floatx4 v1 = *(const floatx4*)(src + 4);
        short8 s;
#pragma unroll
        for (int e = 0; e < 4; ++e) { s[e] = f2bf(v0[e]); s[4 + e] = f2bf(v1[e]); }
        int byte = (c * 16) ^ ((jl & 7) << 4);   // involutive swizzle
        *(short8*)((char*)lds + byte) = s;
    }
    __syncthreads();

    int w    = t >> 6;
    int l    = t & 63;
    int tm   = rb * 4 + w;                   // row tile 0..627
    int arow = tm * 16 + (l & 15);
    int rcl  = min(arow, NROW - 1);
    int kc   = (l >> 4) * 8;
    const float* A = be + (size_t)rcl * DIM;

    floatx4 acc[4] = {{0,0,0,0},{0,0,0,0},{0,0,0,0},{0,0,0,0}};
#pragma unroll
    for (int k0 = 0; k0 < DIM; k0 += 32) {
        floatx4 a0 = *(const floatx4*)(A + k0 + kc);
        floatx4 a1 = *(const floatx4*)(A + k0 + kc + 4);
        short8 av;
#pragma unroll
        for (int e = 0; e < 4; ++e) { av[e] = f2bf(a0[e]); av[4 + e] = f2bf(a1[e]); }
        if (q == 0 && arow < NROW)
            *(short8*)((unsigned short*)beb + (size_t)arow * DIM + k0 + kc) = av;
#pragma unroll
        for (int tt = 0; tt < 4; ++tt) {
            int jl   = tt * 16 + (l & 15);
            int byte = (jl * 512 + (k0 + kc) * 2) ^ ((jl & 7) << 4);
            short8 bv = *(const short8*)((char*)lds + byte);
            acc[tt] = __builtin_amdgcn_mfma_f32_16x16x32_bf16(av, bv, acc[tt], 0, 0, 0);
        }
    }
    // C/D layout: col = lane&15, row = (lane>>4)*4 + r
    int orow = tm * 16 + ((l >> 4) << 2);
#pragma unroll
    for (int tt = 0; tt < 4; ++tt) {
        int col = q * 64 + tt * 16 + (l & 15);       // global output col
        float badd = (col < ADIM) ? bias[col] : 0.f; // self cols get bias
#pragma unroll
        for (int r = 0; r < 4; ++r) {
            if (orow + r < NROW) {
                union { __hip_bfloat16 h; short s; } u;
                u.s = f2bf((acc[tt][r] + badd) * C2L2E);
                SP[(size_t)(orow + r) * DIM + col] = u.h;
            }
        }
    }
}

// ---------------------------------------------------------------------------
// attn helper: tanh + MFMA on a PRELOADED 16-ancestor tile (scores in col 0).
// SP pre-scaled by 2log2e and bias-folded; ssbyp packed bf16.
// No clamp: exp2(+big)->inf -> rcp=0 -> tanh=1; exp2(-big)->0 -> tanh=-1.
// ---------------------------------------------------------------------------
static __device__ __forceinline__ floatx4 tanh_mfma(
    const short8 (&pv)[4], const short8 (&ssbyp)[4], const short8 (&bw)[4]) {
    floatx4 acc = {0.f, 0.f, 0.f, 0.f};
#pragma unroll
    for (int kt = 0; kt < 4; ++kt) {
        short8 af;
#pragma unroll
        for (int i = 0; i < 8; ++i) {
            float y = bf2f((unsigned short)pv[kt][i]) + bf2f((unsigned short)ssbyp[kt][i]);
            float e = EXP2F(y);                        // e = exp(2x)
            float r = __builtin_amdgcn_rcpf(e + 1.f);
            af[i] = f2bf(fmaf(-2.f, r, 1.f));          // tanh(x)
        }
        acc = __builtin_amdgcn_mfma_f32_16x16x32_bf16(af, bw[kt], acc, 0, 0, 0);
    }
    return acc;
}

// ---------------------------------------------------------------------------
// attn: one wave per row n (R4/R12 structure). New vs R15: ALL gathers issue
// at the top — 8 SP-tile loads FIRST, then the 32 E-gathers — so the compiler
// waits only on the SP loads before phase-1 compute (E-loads stay in flight,
// their latency fully hidden under ~700cy of tanh+MFMA). Registers fund the
// in-flight data (~150 VGPR, 12 waves/CU): the direction that has won four
// consecutive rounds (R6's opposite — squeezing — regressed 12%).
// ---------------------------------------------------------------------------
__global__ __launch_bounds__(256, 4) void attn_kernel(
    const int*   __restrict__ anc,
    const float* __restrict__ mask,
    const float* __restrict__ Ww,
    const __hip_bfloat16* __restrict__ SP,
    const __hip_bfloat16* __restrict__ beb,
    float* __restrict__ out) {
    int tid = blockIdx.x * 256 + threadIdx.x;
    int l   = tid & 63;
    int n   = __builtin_amdgcn_readfirstlane(tid >> 6);
    int kc  = (l >> 4) * 8;
    const unsigned short* SPu = (const unsigned short*)SP;

    const int*   ancn = anc  + n * MANC;
    const float* mrow = mask + n * MANC;
    bool has2 = mrow[16] != 0.f;             // wave-uniform: any of m=16..31 live?

    // ---- issue BOTH score tiles' SP gathers first ----
    int m0 = l & 15;
    int j0 = ancn[m0];
    int j1 = has2 ? ancn[16 + m0] : j0;      // clamped addr when tile-1 dead
    const unsigned short* p0 = SPu + (size_t)j0 * DIM + ADIM + kc;
    const unsigned short* p1 = SPu + (size_t)j1 * DIM + ADIM + kc;
    short8 pv0[4], pv1[4];
#pragma unroll
    for (int kt = 0; kt < 4; ++kt) {
        pv0[kt] = *(const short8*)(p0 + kt * 32);
        pv1[kt] = *(const short8*)(p1 + kt * 32);
    }

    // ---- then ALL 32 phase-2 E-gathers: latency hides under phase-1 ----
    const unsigned short* ebase = (const unsigned short*)beb + (size_t)l * 4;
    uint2v dvs[MANC];
#pragma unroll
    for (int m = 0; m < MANC; ++m)
        dvs[m] = *(const uint2v*)(ebase + (size_t)ancn[m] * DIM);

    // ssbyp[kt] = pre-baked bf16 2log2e*(self_proj[n]+bias), packed
    short8 ssbyp[4];
#pragma unroll
    for (int kt = 0; kt < 4; ++kt)
        ssbyp[kt] = *(const short8*)(SPu + (size_t)n * DIM + kt * 32 + kc);

    // B-frag: B[k][c] = (c==0) ? Ww[k] : 0
    float keep = ((l & 15) == 0) ? 1.f : 0.f;
    short8 bw[4];
#pragma unroll
    for (int kt = 0; kt < 4; ++kt) {
        floatx4 w0 = *(const floatx4*)(Ww + kt * 32 + kc);
        floatx4 w1 = *(const floatx4*)(Ww + kt * 32 + kc + 4);
#pragma unroll
        for (int i = 0; i < 8; ++i)
            bw[kt][i] = f2bf(((i < 4) ? w0[i & 3] : w1[i & 3]) * keep);
    }

    __builtin_amdgcn_s_setprio(1);
    floatx4 acc0 = tanh_mfma(pv0, ssbyp, bw);
    floatx4 acc1 = {0.f, 0.f, 0.f, 0.f};
    if (has2)
        acc1 = tanh_mfma(pv1, ssbyp, bw);
    __builtin_amdgcn_s_setprio(0);

    // scores in lanes (l&15)==0: rows rb..rb+3 (tile0), 16+rb..16+rb+3 (tile1)
    int rb = (l >> 4) << 2;
    float s0[4], s1[4];
#pragma unroll
    for (int r = 0; r < 4; ++r) {
        s0[r] = acc0[r] * mrow[rb + r];
        s1[r] = acc1[r] * mrow[16 + rb + r];
    }
    float mx = s0[0];
#pragma unroll
    for (int r = 0; r < 4; ++r) { mx = fmaxf(mx, s0[r]); mx = fmaxf(mx, s1[r]); }
    mx = fmaxf(mx, __shfl_xor(mx, 16, 64));
    mx = fmaxf(mx, __shfl_xor(mx, 32, 64));
    float nm = -mx * L2E;
    float wn0[4], wn1[4], tot = 0.f;
#pragma unroll
    for (int r = 0; r < 4; ++r) {
        wn0[r] = EXP2F(fmaf(s0[r], L2E, nm)); tot += wn0[r];
        wn1[r] = EXP2F(fmaf(s1[r], L2E, nm)); tot += wn1[r];
    }
    tot += __shfl_xor(tot, 16, 64);
    tot += __shfl_xor(tot, 32, 64);
    tot = __shfl(tot, 0, 64);                // lane 0 holds the true sum
    float inv = __builtin_amdgcn_rcpf(tot);

    // Phase 2: G[n] = (sum_m wn[m] * E[j_m]) * inv; data already in registers
    float a0 = 0.f, a1 = 0.f, a2 = 0.f, a3 = 0.f;
#pragma unroll
    for (int m = 0; m < MANC; ++m) {
        int src = ((m & 15) >> 2) << 4;      // holder lane of row m
        float wm = (m < 16) ? __shfl(wn0[m & 3], src, 64)
                            : __shfl(wn1[m & 3], src, 64);
        uint2v dv = dvs[m];
        a0 = fmaf(wm, __uint_as_float(dv.x << 16),          a0);
        a1 = fmaf(wm, __uint_as_float(dv.x & 0xffff0000u),  a1);
        a2 = fmaf(wm, __uint_as_float(dv.y << 16),          a2);
        a3 = fmaf(wm, __uint_as_float(dv.y & 0xffff0000u),  a3);
    }
    floatx4 res = {a0 * inv, a1 * inv, a2 * inv, a3 * inv};
    *(floatx4*)(out + (size_t)n * DIM + l * 4) = res;
}

// ---------------------------------------------------------------------------
extern "C" void kernel_launch(void* const* d_in, const int* in_sizes, int n_in,
                              void* d_out, int out_size, void* d_ws, size_t ws_size,
                              hipStream_t stream) {
    const float* be   = (const float*)d_in[0];
    const int*   anc  = (const int*)d_in[1];
    const float* mask = (const float*)d_in[2];
    const float* Wp   = (const float*)d_in[3];
    const float* bias = (const float*)d_in[4];
    const float* Ww   = (const float*)d_in[5];
    float* out = (float*)d_out;

    // ws: [0, 5.12M) SP bf16 | [5.12M, 10.24M) beb bf16
    __hip_bfloat16* SPb = (__hip_bfloat16*)d_ws;
    __hip_bfloat16* beb = (__hip_bfloat16*)((char*)d_ws + (size_t)NROW * DIM * 2);

    proj_kernel<<<628, 256, 0, stream>>>(be, Wp, bias, SPb, beb);
    attn_kernel<<<2500, 256, 0, stream>>>(anc, mask, Ww, SPb, beb, out);
}

// Round 17
// 45.716 us; speedup vs baseline: 1.1734x; 1.1734x over previous
//
#include <hip/hip_runtime.h>
#include <hip/hip_bf16.h>

// Problem constants (N, M, D, A) = (10000, 32, 256, 128)
#define NROW 10000
#define MANC 32
#define DIM  256
#define ADIM 128

typedef __attribute__((ext_vector_type(8))) short short8;
typedef __attribute__((ext_vector_type(4))) float floatx4;
typedef __attribute__((ext_vector_type(2))) unsigned int uint2v;

#if __has_builtin(__builtin_amdgcn_exp2f)
#define EXP2F(x) __builtin_amdgcn_exp2f(x)
#else
#define EXP2F(x) __expf((x) * 0.69314718055994531f)
#endif

#define C2L2E 2.8853900817779268f   // 2*log2(e)
#define L2E   1.4426950408889634f   // log2(e)

static __device__ __forceinline__ short f2bf(float x) {
    union { __hip_bfloat16 h; short s; } u;
    u.h = __float2bfloat16(x);
    return u.s;
}
static __device__ __forceinline__ float bf2f(unsigned short u) {
    return __uint_as_float(((unsigned int)u) << 16);
}

// ---------------------------------------------------------------------------
// proj: SP[n][j] = be[n] . W2[j], PRE-BAKED: self cols get (acc+bias)*2log2e,
// anc cols get acc*2log2e (bias folded in f32 before the single bf16 round).
// Block = 4 waves = 64 rows x 64-col quarter; W staged via XOR-swizzled LDS;
// q==0 blocks emit beb as a side product.
// ---------------------------------------------------------------------------
__global__ __launch_bounds__(256) void proj_kernel(
    const float* __restrict__ be, const float* __restrict__ Wp,
    const float* __restrict__ bias,
    __hip_bfloat16* __restrict__ SP, __hip_bfloat16* __restrict__ beb) {
    __shared__ short lds[64 * 256];          // 32 KB: 64 W2-rows x 256 k (bf16)
    int q  = blockIdx.x & 3;                 // col quarter
    int rb = blockIdx.x >> 2;                // row block 0..156
    int t  = threadIdx.x;

    // ---- stage W quarter: rows j = q*64 .. q*64+63 ----
#pragma unroll
    for (int i = 0; i < 8; ++i) {
        int c  = i * 256 + t;                // 16B chunk id 0..2047
        int jl = c >> 5;                     // local row 0..63
        int e0 = (c & 31) * 8;               // elem offset 0..248
        int j  = q * 64 + jl;
        const float* src = (j < ADIM) ? (Wp + (size_t)j * (2 * DIM) + e0)
                                      : (Wp + (size_t)(j - ADIM) * (2 * DIM) + DIM + e0);
        floatx4 v0 = *(const floatx4*)src;
        floatx4 v1 = *(const floatx4*)(src + 4);
        short8 s;
#pragma unroll
        for (int e = 0; e < 4; ++e) { s[e] = f2bf(v0[e]); s[4 + e] = f2bf(v1[e]); }
        int byte = (c * 16) ^ ((jl & 7) << 4);   // involutive swizzle
        *(short8*)((char*)lds + byte) = s;
    }
    __syncthreads();

    int w    = t >> 6;
    int l    = t & 63;
    int tm   = rb * 4 + w;                   // row tile 0..627
    int arow = tm * 16 + (l & 15);
    int rcl  = min(arow, NROW - 1);
    int kc   = (l >> 4) * 8;
    const float* A = be + (size_t)rcl * DIM;

    floatx4 acc[4] = {{0,0,0,0},{0,0,0,0},{0,0,0,0},{0,0,0,0}};
#pragma unroll
    for (int k0 = 0; k0 < DIM; k0 += 32) {
        floatx4 a0 = *(const floatx4*)(A + k0 + kc);
        floatx4 a1 = *(const floatx4*)(A + k0 + kc + 4);
        short8 av;
#pragma unroll
        for (int e = 0; e < 4; ++e) { av[e] = f2bf(a0[e]); av[4 + e] = f2bf(a1[e]); }
        if (q == 0 && arow < NROW)
            *(short8*)((unsigned short*)beb + (size_t)arow * DIM + k0 + kc) = av;
#pragma unroll
        for (int tt = 0; tt < 4; ++tt) {
            int jl   = tt * 16 + (l & 15);
            int byte = (jl * 512 + (k0 + kc) * 2) ^ ((jl & 7) << 4);
            short8 bv = *(const short8*)((char*)lds + byte);
            acc[tt] = __builtin_amdgcn_mfma_f32_16x16x32_bf16(av, bv, acc[tt], 0, 0, 0);
        }
    }
    // C/D layout: col = lane&15, row = (lane>>4)*4 + r
    int orow = tm * 16 + ((l >> 4) << 2);
#pragma unroll
    for (int tt = 0; tt < 4; ++tt) {
        int col = q * 64 + tt * 16 + (l & 15);       // global output col
        float badd = (col < ADIM) ? bias[col] : 0.f; // self cols get bias
#pragma unroll
        for (int r = 0; r < 4; ++r) {
            if (orow + r < NROW) {
                union { __hip_bfloat16 h; short s; } u;
                u.s = f2bf((acc[tt][r] + badd) * C2L2E);
                SP[(size_t)(orow + r) * DIM + col] = u.h;
            }
        }
    }
}

// ---------------------------------------------------------------------------
// attn helper: tanh + MFMA on a PRELOADED 16-ancestor tile (scores in col 0).
// SP pre-scaled by 2log2e and bias-folded; ssbyp packed bf16.
// No clamp: exp2(+big)->inf -> rcp=0 -> tanh=1; exp2(-big)->0 -> tanh=-1.
// ---------------------------------------------------------------------------
static __device__ __forceinline__ floatx4 tanh_mfma(
    const short8 (&pv)[4], const short8 (&ssbyp)[4], const short8 (&bw)[4]) {
    floatx4 acc = {0.f, 0.f, 0.f, 0.f};
#pragma unroll
    for (int kt = 0; kt < 4; ++kt) {
        short8 af;
#pragma unroll
        for (int i = 0; i < 8; ++i) {
            float y = bf2f((unsigned short)pv[kt][i]) + bf2f((unsigned short)ssbyp[kt][i]);
            float e = EXP2F(y);                        // e = exp(2x)
            float r = __builtin_amdgcn_rcpf(e + 1.f);
            af[i] = f2bf(fmaf(-2.f, r, 1.f));          // tanh(x)
        }
        acc = __builtin_amdgcn_mfma_f32_16x16x32_bf16(af, bw[kt], acc, 0, 0, 0);
    }
    return acc;
}

// ---------------------------------------------------------------------------
// attn: one wave per row n (R4/R12 structure; R15 prefetch schedule — the
// measured optimum). BOTH score tiles' SP gathers issue up front (tile-1
// addr clamped when masked) so tile-1's latency hides under tile-0 compute;
// phase-2 E-gathers issue after phase-1 (before softmax) — hoisting them any
// earlier exceeds the 128-VGPR budget and spills (R16: −17%).
// ---------------------------------------------------------------------------
__global__ __launch_bounds__(256, 4) void attn_kernel(
    const int*   __restrict__ anc,
    const float* __restrict__ mask,
    const float* __restrict__ Ww,
    const __hip_bfloat16* __restrict__ SP,
    const __hip_bfloat16* __restrict__ beb,
    float* __restrict__ out) {
    int tid = blockIdx.x * 256 + threadIdx.x;
    int l   = tid & 63;
    int n   = __builtin_amdgcn_readfirstlane(tid >> 6);
    int kc  = (l >> 4) * 8;
    const unsigned short* SPu = (const unsigned short*)SP;

    // ssbyp[kt] = pre-baked bf16 2log2e*(self_proj[n]+bias), packed
    short8 ssbyp[4];
#pragma unroll
    for (int kt = 0; kt < 4; ++kt)
        ssbyp[kt] = *(const short8*)(SPu + (size_t)n * DIM + kt * 32 + kc);

    // B-frag: B[k][c] = (c==0) ? Ww[k] : 0
    float keep = ((l & 15) == 0) ? 1.f : 0.f;
    short8 bw[4];
#pragma unroll
    for (int kt = 0; kt < 4; ++kt) {
        floatx4 w0 = *(const floatx4*)(Ww + kt * 32 + kc);
        floatx4 w1 = *(const floatx4*)(Ww + kt * 32 + kc + 4);
#pragma unroll
        for (int i = 0; i < 8; ++i)
            bw[kt][i] = f2bf(((i < 4) ? w0[i & 3] : w1[i & 3]) * keep);
    }

    const int*   ancn = anc  + n * MANC;
    const float* mrow = mask + n * MANC;
    bool has2 = mrow[16] != 0.f;             // wave-uniform: any of m=16..31 live?

    // ---- issue BOTH tiles' SP gathers up front ----
    int m0 = l & 15;
    int j0 = ancn[m0];
    int j1 = has2 ? ancn[16 + m0] : j0;      // clamped addr when tile-1 dead
    const unsigned short* p0 = SPu + (size_t)j0 * DIM + ADIM + kc;
    const unsigned short* p1 = SPu + (size_t)j1 * DIM + ADIM + kc;
    short8 pv0[4], pv1[4];
#pragma unroll
    for (int kt = 0; kt < 4; ++kt) {
        pv0[kt] = *(const short8*)(p0 + kt * 32);
        pv1[kt] = *(const short8*)(p1 + kt * 32);
    }

    __builtin_amdgcn_s_setprio(1);
    floatx4 acc0 = tanh_mfma(pv0, ssbyp, bw);
    floatx4 acc1 = {0.f, 0.f, 0.f, 0.f};
    if (has2)
        acc1 = tanh_mfma(pv1, ssbyp, bw);
    __builtin_amdgcn_s_setprio(0);

    // Issue ALL 32 phase-2 E-gathers now — softmax below covers their latency.
    const unsigned short* ebase = (const unsigned short*)beb + (size_t)l * 4;
    uint2v dvs[MANC];
#pragma unroll
    for (int m = 0; m < MANC; ++m)
        dvs[m] = *(const uint2v*)(ebase + (size_t)ancn[m] * DIM);

    // scores in lanes (l&15)==0: rows rb..rb+3 (tile0), 16+rb..16+rb+3 (tile1)
    int rb = (l >> 4) << 2;
    float s0[4], s1[4];
#pragma unroll
    for (int r = 0; r < 4; ++r) {
        s0[r] = acc0[r] * mrow[rb + r];
        s1[r] = acc1[r] * mrow[16 + rb + r];
    }
    float mx = s0[0];
#pragma unroll
    for (int r = 0; r < 4; ++r) { mx = fmaxf(mx, s0[r]); mx = fmaxf(mx, s1[r]); }
    mx = fmaxf(mx, __shfl_xor(mx, 16, 64));
    mx = fmaxf(mx, __shfl_xor(mx, 32, 64));
    float nm = -mx * L2E;
    float wn0[4], wn1[4], tot = 0.f;
#pragma unroll
    for (int r = 0; r < 4; ++r) {
        wn0[r] = EXP2F(fmaf(s0[r], L2E, nm)); tot += wn0[r];
        wn1[r] = EXP2F(fmaf(s1[r], L2E, nm)); tot += wn1[r];
    }
    tot += __shfl_xor(tot, 16, 64);
    tot += __shfl_xor(tot, 32, 64);
    tot = __shfl(tot, 0, 64);                // lane 0 holds the true sum
    float inv = __builtin_amdgcn_rcpf(tot);

    // Phase 2: G[n] = (sum_m wn[m] * E[j_m]) * inv; data already in registers
    float a0 = 0.f, a1 = 0.f, a2 = 0.f, a3 = 0.f;
#pragma unroll
    for (int m = 0; m < MANC; ++m) {
        int src = ((m & 15) >> 2) << 4;      // holder lane of row m
        float wm = (m < 16) ? __shfl(wn0[m & 3], src, 64)
                            : __shfl(wn1[m & 3], src, 64);
        uint2v dv = dvs[m];
        a0 = fmaf(wm, __uint_as_float(dv.x << 16),          a0);
        a1 = fmaf(wm, __uint_as_float(dv.x & 0xffff0000u),  a1);
        a2 = fmaf(wm, __uint_as_float(dv.y << 16),          a2);
        a3 = fmaf(wm, __uint_as_float(dv.y & 0xffff0000u),  a3);
    }
    floatx4 res = {a0 * inv, a1 * inv, a2 * inv, a3 * inv};
    *(floatx4*)(out + (size_t)n * DIM + l * 4) = res;
}

// ---------------------------------------------------------------------------
extern "C" void kernel_launch(void* const* d_in, const int* in_sizes, int n_in,
                              void* d_out, int out_size, void* d_ws, size_t ws_size,
                              hipStream_t stream) {
    const float* be   = (const float*)d_in[0];
    const int*   anc  = (const int*)d_in[1];
    const float* mask = (const float*)d_in[2];
    const float* Wp   = (const float*)d_in[3];
    const float* bias = (const float*)d_in[4];
    const float* Ww   = (const float*)d_in[5];
    float* out = (float*)d_out;

    // ws: [0, 5.12M) SP bf16 | [5.12M, 10.24M) beb bf16
    __hip_bfloat16* SPb = (__hip_bfloat16*)d_ws;
    __hip_bfloat16* beb = (__hip_bfloat16*)((char*)d_ws + (size_t)NROW * DIM * 2);

    proj_kernel<<<628, 256, 0, stream>>>(be, Wp, bias, SPb, beb);
    attn_kernel<<<2500, 256, 0, stream>>>(anc, mask, Ww, SPb, beb, out);
}